// Round 15
// baseline (83.016 us; speedup 1.0000x reference)
//
#include <hip/hip_runtime.h>
#include <hip/hip_bf16.h>

typedef unsigned short u16;
typedef __attribute__((ext_vector_type(4))) short short4v;
typedef __attribute__((ext_vector_type(8))) short short8;
typedef __attribute__((ext_vector_type(4))) float f32x4;

#define HID 128
#define WNUMEL 3072
#define OUTD 144

// ---------- fused pre-pass: W2 swizzle | MFMA-MLP | sh + linked-list build ----------
__global__ void k_pre(const float* __restrict__ W2, __hip_bfloat16* __restrict__ W2s,
                      const float* __restrict__ es, const float* __restrict__ W1,
                      const float* __restrict__ b1, __hip_bfloat16* __restrict__ h2s,
                      const float* __restrict__ ev, const int* __restrict__ dst,
                      float* __restrict__ shb, int* __restrict__ head,
                      int* __restrict__ nxt, int E, int NW, int NM) {
  __shared__ u16 wlds[4096];           // 8 KB: W1 A-fragments (MLP branch only)
  const int b = blockIdx.x, tid = threadIdx.x;
  if (b < NW) {
    // W2 swizzle: thread <-> (k-octet kh, col n). 8 coalesced reads (lane spans n),
    // ONE 16B store (i = k&7 is contiguous in dest). 192 blocks total.
    int t = b * 256 + tid;             // < 16*3072 = 49152
    int kh = t / WNUMEL, n = t - kh * WNUMEL;
    int s = kh >> 2, h = kh & 3, tt = n >> 4, c = n & 15;
    short8 pk;
#pragma unroll
    for (int i = 0; i < 8; ++i)
      ((u16*)&pk)[i] = __bfloat16_as_ushort(
          __float2bfloat16(W2[(size_t)(8 * kh + i) * WNUMEL + n]));
    *(short8*)(W2s + ((size_t)(tt * 4 + s) * 64 + (c + 16 * h)) * 8) = pk;
  } else if (b < NW + NM) {
    // MLP via MFMA, SWAPPED operands: C = W1^T-ish rows (h) x cols (e).
    // Each lane holds 4 contiguous h for one e -> one 8B store per N-tile.
    const int e0 = (b - NW) * 64;
    const int w = tid >> 6, l = tid & 63;
    const int c = l & 15, g = l >> 4;  // g = k-octet group
    const int kb = 8 * g;
    // stage W1 fragments (wave w does nt = 2w, 2w+1): lane holds W1[kb+i][nt*16+c]
#pragma unroll
    for (int q = 0; q < 2; ++q) {
      int nt = 2 * w + q;
      int n = nt * 16 + c;
#pragma unroll
      for (int i = 0; i < 8; ++i)
        wlds[(nt * 64 + l) * 8 + i] = __bfloat16_as_ushort(
            __float2bfloat16(W1[(size_t)(kb + i) * HID + n]));
    }
    // es B-fragment: lane holds es[e = e0+w*16+c][kb+i]
    short8 ef = {0, 0, 0, 0, 0, 0, 0, 0};
    const int e = e0 + w * 16 + c;
    if (e < E) {
      const float4 p0 = *(const float4*)(es + (size_t)e * 32 + kb);
      const float4 p1 = *(const float4*)(es + (size_t)e * 32 + kb + 4);
#pragma unroll
      for (int i = 0; i < 4; ++i) {
        ((u16*)&ef)[i]     = __bfloat16_as_ushort(__float2bfloat16((&p0.x)[i]));
        ((u16*)&ef)[4 + i] = __bfloat16_as_ushort(__float2bfloat16((&p1.x)[i]));
      }
    }
    __syncthreads();
#pragma unroll
    for (int nt = 0; nt < 8; ++nt) {
      short8 wf = *(const short8*)(wlds + (nt * 64 + l) * 8);
      const float4 b1q = *(const float4*)(b1 + nt * 16 + g * 4);
      f32x4 acc = {b1q.x, b1q.y, b1q.z, b1q.w};
      acc = __builtin_amdgcn_mfma_f32_16x16x32_bf16(wf, ef, acc, 0, 0, 0);
      // C: col = lane&15 = e_lo, row = g*4+j = h_lo; h = nt*16 + g*4 + j
      if (e < E) {
        int s = nt >> 1;
        int hh = (2 * nt + (g >> 1)) & 3;
        int i0 = 4 * (g & 1);
        short4v pk;
#pragma unroll
        for (int j = 0; j < 4; ++j) {
          float a = acc[j];
          float z = a / (1.f + expf(-a)) * 0.125f;    // silu, fold 1/sqrt(64)
          ((u16*)&pk)[j] = __bfloat16_as_ushort(__float2bfloat16(z));
        }
        *(short4v*)(h2s + ((size_t)(e >> 4) * 4 + s) * 512 +
                    ((e & 15) + 16 * hh) * 8 + i0) = pk;
      }
    }
  } else {
    int e = (b - NW - NM) * 256 + tid;
    if (e >= E) return;
    float vx = ev[e * 3 + 0], vy = ev[e * 3 + 1], vz = ev[e * 3 + 2];
    float nrm = fmaxf(sqrtf(vx * vx + vy * vy + vz * vz), 1e-9f);
    float x = vx / nrm, y = vy / nrm, z = vz / nrm;
    const float SQ3 = 1.7320508075688772f, SQ5 = 2.2360679774997896f,
                SQ15 = 3.872983346207417f;
    float* sp = shb + (size_t)e * 9;
    sp[0] = 1.f;
    sp[1] = SQ3 * x; sp[2] = SQ3 * y; sp[3] = SQ3 * z;
    sp[4] = SQ15 * x * y; sp[5] = SQ15 * y * z;
    sp[6] = 0.5f * SQ5 * (3.f * z * z - 1.f);
    sp[7] = SQ15 * x * z;
    sp[8] = 0.5f * SQ15 * (x * x - y * y);
    nxt[e] = atomicExch(&head[dst[e]], e);           // per-dst linked list
  }
}

// ---------- fused GEMM + x-contraction -> feat[E][48]  (champion, frozen) ----------
__global__ __launch_bounds__(256, 2) void k_gemm(
    const u16* __restrict__ h2s, const u16* __restrict__ W2s,
    const float* __restrict__ hsrc, const int* __restrict__ srci,
    const float* __restrict__ b2, float* __restrict__ feat_out, int E) {
  __shared__ float lds[4160];          // xT[64u][64e] (16KB), then fl[4][1040]
  float* xT = lds;
  float* fl = lds;
  const int tid = threadIdx.x, lane = tid & 63, wave = tid >> 6;
  const int blk = blockIdx.x, l3 = blockIdx.y;
  const int c = lane & 15, g = lane >> 4;

  // stage x transposed (wave w stages u-rows [w*16, w*16+16))
  {
    int e = lane, u0 = wave * 16;
    int eg = min(blk * 64 + e, E - 1);
    const float* xr = hsrc + (size_t)srci[eg] * 64 + u0;
#pragma unroll
    for (int k = 0; k < 16; ++k) xT[(u0 + k) * 64 + e] = xr[k];
  }
  // A fragments: 4 M-tiles x 4 k-steps
  short8 af[4][4];
#pragma unroll
  for (int mt = 0; mt < 4; ++mt)
#pragma unroll
    for (int s = 0; s < 4; ++s)
      af[mt][s] = *(const short8*)(h2s + ((size_t)((blk * 4 + mt) * 4 + s) * 64 + lane) * 8);
  __syncthreads();

  float feat[4][4] = {};               // [mt][j], this l-path, this wave's u-range
  const int T0 = l3 * 64 + wave * 16;
  const u16* Bg = W2s + (size_t)T0 * 2048;
  const float* b2g = b2 + T0 * 16 + c;

#pragma unroll
  for (int k = 0; k < 16; ++k) {       // wave's 16 N-tiles, no barriers
    short8 bf[4];
#pragma unroll
    for (int s = 0; s < 4; ++s)
      bf[s] = *(const short8*)(Bg + ((size_t)(k * 4 + s) * 64 + lane) * 8);
    float b2v = 0.125f * b2g[k * 16];
#pragma unroll
    for (int mt = 0; mt < 4; ++mt) {
      f32x4 acc = {b2v, b2v, b2v, b2v};
#pragma unroll
      for (int s = 0; s < 4; ++s)
        acc = __builtin_amdgcn_mfma_f32_16x16x32_bf16(af[mt][s], bf[s], acc, 0, 0, 0);
      const float4 xv = *(const float4*)&xT[(wave * 16 + k) * 64 + mt * 16 + g * 4];
#pragma unroll
      for (int j = 0; j < 4; ++j)
        feat[mt][j] = fmaf((&xv.x)[j], acc[j], feat[mt][j]);
    }
  }

  // cross-wave feat reduction in LDS (reuses xT space — barrier first)
  __syncthreads();
#pragma unroll
  for (int mt = 0; mt < 4; ++mt)
#pragma unroll
    for (int j = 0; j < 4; ++j)
      fl[wave * 1040 + (mt * 16 + g * 4 + j) * 16 + c] = feat[mt][j];
  __syncthreads();

  // epilogue: sum the 4 wave-partials, store compact feat slice for this l3
#pragma unroll
  for (int r = 0; r < 4; ++r) {
    int p = r * 256 + tid;             // 1024 = 64 edges x 16 v
    int eloc = p >> 4, v = p & 15;
    float f = fl[p] + fl[1040 + p] + fl[2080 + p] + fl[3120 + p];
    int e = blk * 64 + eloc;
    if (e < E) feat_out[(size_t)e * 48 + l3 * 16 + v] = f;
  }
}

// ---------- gather: 16 lanes per dst (4 chains chase in parallel per wave) ----------
__global__ void k_gather(const float* __restrict__ feat, const float* __restrict__ shb,
                         const int* __restrict__ head, const int* __restrict__ nxt,
                         float* __restrict__ out, int n_dst) {
  const int tid = threadIdx.x;
  const int d = blockIdx.x * 16 + (tid >> 4);
  const int q = tid & 15;
  if (d >= n_dst) return;
  // lane handles output floats [q*9, q*9+9)
  int fi[9], si[9];
#pragma unroll
  for (int r = 0; r < 9; ++r) {
    int o = q * 9 + r;
    if (o < 16)      { fi[r] = o;                 si[r] = 0; }        // sh[0] == 1
    else if (o < 64) { int id = o - 16; fi[r] = 16 + id / 3; si[r] = 1 + id % 3; }
    else             { int id = o - 64; fi[r] = 32 + id / 5; si[r] = 4 + id % 5; }
  }
  int e = head[d];                     // uniform within the 16-lane group
  float acc[9] = {};
  int deg = 0;
  while (e >= 0) {
    int en = nxt[e];                   // issue next hop first (chase overlap)
    const float* fp = feat + (size_t)e * 48;
    const float* sp = shb + (size_t)e * 9;
#pragma unroll
    for (int r = 0; r < 9; ++r)
      acc[r] = fmaf(fp[fi[r]], sp[si[r]], acc[r]);
    ++deg;
    e = en;
  }
  const float inv = 1.f / (float)max(deg, 1);
  float* ob = out + (size_t)d * OUTD + q * 9;
#pragma unroll
  for (int r = 0; r < 9; ++r) ob[r] = acc[r] * inv;
}

extern "C" void kernel_launch(void* const* d_in, const int* in_sizes, int n_in,
                              void* d_out, int out_size, void* d_ws, size_t ws_size,
                              hipStream_t stream) {
  const float* h_src        = (const float*)d_in[0];
  const float* edge_vec     = (const float*)d_in[1];
  const float* edge_scalars = (const float*)d_in[2];
  const float* W1           = (const float*)d_in[3];
  const float* b1           = (const float*)d_in[4];
  const float* W2           = (const float*)d_in[5];
  const float* b2           = (const float*)d_in[6];
  const int*   src_idx      = (const int*)d_in[7];
  const int*   dst_idx      = (const int*)d_in[8];

  const int E = in_sizes[1] / 3;
  const int n_dst = out_size / OUTD;
  const int nblk64 = (E + 63) / 64;
  const size_t E_pad = (size_t)nblk64 * 64;

  char* w = (char*)d_ws;
  auto al = [](size_t x) { return (x + 255) & ~(size_t)255; };
  size_t o = 0;
  float* shb = (float*)(w + o);                   o += al(E_pad * 9 * 4);
  __hip_bfloat16* h2s = (__hip_bfloat16*)(w + o); o += al(E_pad * 128 * 2);
  __hip_bfloat16* W2s = (__hip_bfloat16*)(w + o); o += al((size_t)128 * 3072 * 2);
  float* featb = (float*)(w + o);                 o += al(E_pad * 48 * 4);
  int* head  = (int*)(w + o);                     o += al((size_t)n_dst * 4);
  int* nxt   = (int*)(w + o);                     o += al((size_t)E * 4);

  hipMemsetAsync(head, 0xFF, (size_t)n_dst * 4, stream);   // head = -1

  const int NW = (16 * WNUMEL) / 256;             // 192 vectorized w2s blocks
  const int NM = (E + 63) / 64;                   // mfma-mlp blocks (64 edges each)
  const int NL = (E + 255) / 256;                 // sh + list blocks
  k_pre<<<NW + NM + NL, 256, 0, stream>>>(W2, W2s, edge_scalars, W1, b1, h2s,
                                          edge_vec, dst_idx, shb, head, nxt, E, NW, NM);
  dim3 gg(nblk64, 3);
  k_gemm<<<gg, 256, 0, stream>>>((const u16*)h2s, (const u16*)W2s, h_src, src_idx,
                                 b2, featb, E);
  k_gather<<<(n_dst + 15) / 16, 256, 0, stream>>>(featb, shb, head, nxt,
                                                  (float*)d_out, n_dst);
}

// Round 16
// 77.949 us; speedup vs baseline: 1.0650x; 1.0650x over previous
//
#include <hip/hip_runtime.h>
#include <hip/hip_bf16.h>

typedef unsigned short u16;
typedef __attribute__((ext_vector_type(8))) short short8;
typedef __attribute__((ext_vector_type(4))) float f32x4;

#define HID 128
#define WNUMEL 3072
#define OUTD 144

// ---------- fused pre-pass: W2 swizzle(vec) | MFMA-MLP | sh + linked-list build ----------
__global__ void k_pre(const float* __restrict__ W2, __hip_bfloat16* __restrict__ W2s,
                      const float* __restrict__ es, const float* __restrict__ W1,
                      const float* __restrict__ b1, __hip_bfloat16* __restrict__ h2s,
                      const float* __restrict__ ev, const int* __restrict__ dst,
                      float* __restrict__ shb, int* __restrict__ head,
                      int* __restrict__ nxt, int E, int NW, int NM) {
  __shared__ u16 wlds[4096];           // 8 KB: W1 B-fragments (MLP branch only)
  const int b = blockIdx.x, tid = threadIdx.x;
  if (b < NW) {
    // W2 swizzle: thread <-> (k-octet kh, col n). 8 coalesced reads (lane spans n),
    // ONE 16B store (i = k&7 is contiguous in dest). 192 blocks total.
    int t = b * 256 + tid;             // < 16*3072 = 49152
    int kh = t / WNUMEL, n = t - kh * WNUMEL;
    int s = kh >> 2, h = kh & 3, tt = n >> 4, c = n & 15;
    short8 pk;
#pragma unroll
    for (int i = 0; i < 8; ++i)
      ((u16*)&pk)[i] = __bfloat16_as_ushort(
          __float2bfloat16(W2[(size_t)(8 * kh + i) * WNUMEL + n]));
    *(short8*)(W2s + ((size_t)(tt * 4 + s) * 64 + (c + 16 * h)) * 8) = pk;
  } else if (b < NW + NM) {
    // MLP via MFMA (R14 champion form): h2 = silu(es@W1+b1)*0.125
    const int e0 = (b - NW) * 64;
    const int w = tid >> 6, l = tid & 63;
    const int c = l & 15, kb = 8 * ((l >> 4) & 3);
    // stage W1 fragments (wave w does nt = 2w, 2w+1)
#pragma unroll
    for (int q = 0; q < 2; ++q) {
      int nt = 2 * w + q;
      int n = nt * 16 + c;
#pragma unroll
      for (int i = 0; i < 8; ++i)
        wlds[(nt * 64 + l) * 8 + i] = (u16)__bfloat16_as_ushort(
            __float2bfloat16(W1[(kb + i) * HID + n]));
    }
    // es A-fragment for this wave's 16 edges
    short8 ef = {0, 0, 0, 0, 0, 0, 0, 0};
    {
      int e = e0 + w * 16 + c;
      if (e < E) {
        const float4 p0 = *(const float4*)(es + (size_t)e * 32 + kb);
        const float4 p1 = *(const float4*)(es + (size_t)e * 32 + kb + 4);
        u16* pe = (u16*)&ef;
#pragma unroll
        for (int i = 0; i < 4; ++i) {
          pe[i]     = __bfloat16_as_ushort(__float2bfloat16((&p0.x)[i]));
          pe[4 + i] = __bfloat16_as_ushort(__float2bfloat16((&p1.x)[i]));
        }
      }
    }
    __syncthreads();
#pragma unroll
    for (int nt = 0; nt < 8; ++nt) {
      short8 bf = *(const short8*)(wlds + (nt * 64 + l) * 8);
      float b1v = b1[nt * 16 + c];
      f32x4 acc = {b1v, b1v, b1v, b1v};
      acc = __builtin_amdgcn_mfma_f32_16x16x32_bf16(ef, bf, acc, 0, 0, 0);
      // C layout: col = lane&15 (h_lo), row = (lane>>4)*4+j (e_lo)
      int hh = (2 * nt + (c >> 3)) & 3;
      int s = nt >> 1;
      int i = c & 7;
#pragma unroll
      for (int j = 0; j < 4; ++j) {
        int e = e0 + w * 16 + (l >> 4) * 4 + j;
        if (e < E) {
          float a = acc[j];
          float z = a / (1.f + expf(-a)) * 0.125f;    // silu, fold 1/sqrt(64)
          h2s[((size_t)(e >> 4) * 4 + s) * 512 + ((e & 15) + 16 * hh) * 8 + i] =
              __float2bfloat16(z);
        }
      }
    }
  } else {
    int e = (b - NW - NM) * 256 + tid;
    if (e >= E) return;
    float vx = ev[e * 3 + 0], vy = ev[e * 3 + 1], vz = ev[e * 3 + 2];
    float nrm = fmaxf(sqrtf(vx * vx + vy * vy + vz * vz), 1e-9f);
    float x = vx / nrm, y = vy / nrm, z = vz / nrm;
    const float SQ3 = 1.7320508075688772f, SQ5 = 2.2360679774997896f,
                SQ15 = 3.872983346207417f;
    float* sp = shb + (size_t)e * 9;
    sp[0] = 1.f;
    sp[1] = SQ3 * x; sp[2] = SQ3 * y; sp[3] = SQ3 * z;
    sp[4] = SQ15 * x * y; sp[5] = SQ15 * y * z;
    sp[6] = 0.5f * SQ5 * (3.f * z * z - 1.f);
    sp[7] = SQ15 * x * z;
    sp[8] = 0.5f * SQ15 * (x * x - y * y);
    nxt[e] = atomicExch(&head[dst[e]], e);           // per-dst linked list
  }
}

// ---------- fused GEMM + x-contraction -> feat[E][48]  (champion, frozen) ----------
__global__ __launch_bounds__(256, 2) void k_gemm(
    const u16* __restrict__ h2s, const u16* __restrict__ W2s,
    const float* __restrict__ hsrc, const int* __restrict__ srci,
    const float* __restrict__ b2, float* __restrict__ feat_out, int E) {
  __shared__ float lds[4160];          // xT[64u][64e] (16KB), then fl[4][1040]
  float* xT = lds;
  float* fl = lds;
  const int tid = threadIdx.x, lane = tid & 63, wave = tid >> 6;
  const int blk = blockIdx.x, l3 = blockIdx.y;
  const int c = lane & 15, g = lane >> 4;

  // stage x transposed (wave w stages u-rows [w*16, w*16+16))
  {
    int e = lane, u0 = wave * 16;
    int eg = min(blk * 64 + e, E - 1);
    const float* xr = hsrc + (size_t)srci[eg] * 64 + u0;
#pragma unroll
    for (int k = 0; k < 16; ++k) xT[(u0 + k) * 64 + e] = xr[k];
  }
  // A fragments: 4 M-tiles x 4 k-steps
  short8 af[4][4];
#pragma unroll
  for (int mt = 0; mt < 4; ++mt)
#pragma unroll
    for (int s = 0; s < 4; ++s)
      af[mt][s] = *(const short8*)(h2s + ((size_t)((blk * 4 + mt) * 4 + s) * 64 + lane) * 8);
  __syncthreads();

  float feat[4][4] = {};               // [mt][j], this l-path, this wave's u-range
  const int T0 = l3 * 64 + wave * 16;
  const u16* Bg = W2s + (size_t)T0 * 2048;
  const float* b2g = b2 + T0 * 16 + c;

#pragma unroll
  for (int k = 0; k < 16; ++k) {       // wave's 16 N-tiles, no barriers
    short8 bf[4];
#pragma unroll
    for (int s = 0; s < 4; ++s)
      bf[s] = *(const short8*)(Bg + ((size_t)(k * 4 + s) * 64 + lane) * 8);
    float b2v = 0.125f * b2g[k * 16];
#pragma unroll
    for (int mt = 0; mt < 4; ++mt) {
      f32x4 acc = {b2v, b2v, b2v, b2v};
#pragma unroll
      for (int s = 0; s < 4; ++s)
        acc = __builtin_amdgcn_mfma_f32_16x16x32_bf16(af[mt][s], bf[s], acc, 0, 0, 0);
      const float4 xv = *(const float4*)&xT[(wave * 16 + k) * 64 + mt * 16 + g * 4];
#pragma unroll
      for (int j = 0; j < 4; ++j)
        feat[mt][j] = fmaf((&xv.x)[j], acc[j], feat[mt][j]);
    }
  }

  // cross-wave feat reduction in LDS (reuses xT space — barrier first)
  __syncthreads();
#pragma unroll
  for (int mt = 0; mt < 4; ++mt)
#pragma unroll
    for (int j = 0; j < 4; ++j)
      fl[wave * 1040 + (mt * 16 + g * 4 + j) * 16 + c] = feat[mt][j];
  __syncthreads();

  // epilogue: sum the 4 wave-partials, store compact feat slice for this l3
#pragma unroll
  for (int r = 0; r < 4; ++r) {
    int p = r * 256 + tid;             // 1024 = 64 edges x 16 v
    int eloc = p >> 4, v = p & 15;
    float f = fl[p] + fl[1040 + p] + fl[2080 + p] + fl[3120 + p];
    int e = blk * 64 + eloc;
    if (e < E) feat_out[(size_t)e * 48 + l3 * 16 + v] = f;
  }
}

// ---------- gather: one wave per dst; walk linked list; apply sh; mean ----------
__global__ void k_gather(const float* __restrict__ feat, const float* __restrict__ shb,
                         const int* __restrict__ head, const int* __restrict__ nxt,
                         float* __restrict__ out, int n_dst) {
  int d = blockIdx.x * 4 + (threadIdx.x >> 6);
  int lane = threadIdx.x & 63;
  if (d >= n_dst) return;
  int fi[4], si[4];
#pragma unroll
  for (int r = 0; r < 4; ++r) {
    int o = lane * 4 + r;
    if (o < 16)      { fi[r] = o;                 si[r] = 0; }        // sh[0] == 1
    else if (o < 64) { int id = o - 16; fi[r] = 16 + id / 3; si[r] = 1 + id % 3; }
    else             { int id = o - 64; fi[r] = 32 + id / 5; si[r] = 4 + id % 5; }
  }
  int e = head[d];                     // same addr across lanes -> broadcast load
  float4 acc = {0.f, 0.f, 0.f, 0.f};
  int deg = 0;
  while (e >= 0) {
    int en = nxt[e];                   // issue next-pointer first (chase overlap)
    if (lane < 36) {
      const float* fp = feat + (size_t)e * 48;
      const float* sp = shb + (size_t)e * 9;
#pragma unroll
      for (int r = 0; r < 4; ++r)
        (&acc.x)[r] = fmaf(fp[fi[r]], sp[si[r]], (&acc.x)[r]);
    }
    ++deg;
    e = en;
  }
  if (lane < 36) {
    float inv = 1.f / (float)max(deg, 1);
    acc.x *= inv; acc.y *= inv; acc.z *= inv; acc.w *= inv;
    *(float4*)&out[(size_t)d * OUTD + lane * 4] = acc;
  }
}

extern "C" void kernel_launch(void* const* d_in, const int* in_sizes, int n_in,
                              void* d_out, int out_size, void* d_ws, size_t ws_size,
                              hipStream_t stream) {
  const float* h_src        = (const float*)d_in[0];
  const float* edge_vec     = (const float*)d_in[1];
  const float* edge_scalars = (const float*)d_in[2];
  const float* W1           = (const float*)d_in[3];
  const float* b1           = (const float*)d_in[4];
  const float* W2           = (const float*)d_in[5];
  const float* b2           = (const float*)d_in[6];
  const int*   src_idx      = (const int*)d_in[7];
  const int*   dst_idx      = (const int*)d_in[8];

  const int E = in_sizes[1] / 3;
  const int n_dst = out_size / OUTD;
  const int nblk64 = (E + 63) / 64;
  const size_t E_pad = (size_t)nblk64 * 64;

  char* w = (char*)d_ws;
  auto al = [](size_t x) { return (x + 255) & ~(size_t)255; };
  size_t o = 0;
  float* shb = (float*)(w + o);                   o += al(E_pad * 9 * 4);
  __hip_bfloat16* h2s = (__hip_bfloat16*)(w + o); o += al(E_pad * 128 * 2);
  __hip_bfloat16* W2s = (__hip_bfloat16*)(w + o); o += al((size_t)128 * 3072 * 2);
  float* featb = (float*)(w + o);                 o += al(E_pad * 48 * 4);
  int* head  = (int*)(w + o);                     o += al((size_t)n_dst * 4);
  int* nxt   = (int*)(w + o);                     o += al((size_t)E * 4);

  hipMemsetAsync(head, 0xFF, (size_t)n_dst * 4, stream);   // head = -1

  const int NW = (16 * WNUMEL) / 256;             // 192 vectorized w2s blocks
  const int NM = (E + 63) / 64;                   // mfma-mlp blocks (64 edges each)
  const int NL = (E + 255) / 256;                 // sh + list blocks
  k_pre<<<NW + NM + NL, 256, 0, stream>>>(W2, W2s, edge_scalars, W1, b1, h2s,
                                          edge_vec, dst_idx, shb, head, nxt, E, NW, NM);
  dim3 gg(nblk64, 3);
  k_gemm<<<gg, 256, 0, stream>>>((const u16*)h2s, (const u16*)W2s, h_src, src_idx,
                                 b2, featb, E);
  k_gather<<<(n_dst + 3) / 4, 256, 0, stream>>>(featb, shb, head, nxt,
                                                (float*)d_out, n_dst);
}

// Round 19
// 73.532 us; speedup vs baseline: 1.1290x; 1.0601x over previous
//
#include <hip/hip_runtime.h>
#include <hip/hip_bf16.h>

typedef unsigned short u16;
typedef __attribute__((ext_vector_type(8))) short short8;
typedef __attribute__((ext_vector_type(4))) float f32x4;

#define HID 128
#define WNUMEL 3072
#define OUTD 144

// ---------- pre-pass: W2 swizzle(vec) | MFMA-MLP | head-init ----------
__global__ void k_pre(const float* __restrict__ W2, __hip_bfloat16* __restrict__ W2s,
                      const float* __restrict__ es, const float* __restrict__ W1,
                      const float* __restrict__ b1, __hip_bfloat16* __restrict__ h2s,
                      int* __restrict__ head, int E, int n_dst, int NW, int NM) {
  __shared__ u16 wlds[4096];           // 8 KB: W1 fragments (MLP branch only)
  const int b = blockIdx.x, tid = threadIdx.x;
  if (b < NW) {
    // W2 swizzle: 8 coalesced reads, ONE 16B store. 192 blocks.
    int t = b * 256 + tid;             // < 16*3072
    int kh = t / WNUMEL, n = t - kh * WNUMEL;
    int s = kh >> 2, h = kh & 3, tt = n >> 4, c = n & 15;
    short8 pk;
#pragma unroll
    for (int i = 0; i < 8; ++i)
      ((u16*)&pk)[i] = __bfloat16_as_ushort(
          __float2bfloat16(W2[(size_t)(8 * kh + i) * WNUMEL + n]));
    *(short8*)((u16*)W2s + ((size_t)(tt * 4 + s) * 64 + (c + 16 * h)) * 8) = pk;
  } else if (b < NW + NM) {
    // MLP via MFMA (champion form): h2 = silu(es@W1+b1)*0.125
    const int e0 = (b - NW) * 64;
    const int w = tid >> 6, l = tid & 63;
    const int c = l & 15, kb = 8 * ((l >> 4) & 3);
#pragma unroll
    for (int q = 0; q < 2; ++q) {
      int nt = 2 * w + q;
      int n = nt * 16 + c;
#pragma unroll
      for (int i = 0; i < 8; ++i)
        wlds[(nt * 64 + l) * 8 + i] = (u16)__bfloat16_as_ushort(
            __float2bfloat16(W1[(kb + i) * HID + n]));
    }
    short8 ef = {0, 0, 0, 0, 0, 0, 0, 0};
    {
      int e = e0 + w * 16 + c;
      if (e < E) {
        const float4 p0 = *(const float4*)(es + (size_t)e * 32 + kb);
        const float4 p1 = *(const float4*)(es + (size_t)e * 32 + kb + 4);
        u16* pe = (u16*)&ef;
#pragma unroll
        for (int i = 0; i < 4; ++i) {
          pe[i]     = __bfloat16_as_ushort(__float2bfloat16((&p0.x)[i]));
          pe[4 + i] = __bfloat16_as_ushort(__float2bfloat16((&p1.x)[i]));
        }
      }
    }
    __syncthreads();
#pragma unroll
    for (int nt = 0; nt < 8; ++nt) {
      short8 bf = *(const short8*)(wlds + (nt * 64 + l) * 8);
      float b1v = b1[nt * 16 + c];
      f32x4 acc = {b1v, b1v, b1v, b1v};
      acc = __builtin_amdgcn_mfma_f32_16x16x32_bf16(ef, bf, acc, 0, 0, 0);
      int hh = (2 * nt + (c >> 3)) & 3;
      int s = nt >> 1;
      int i = c & 7;
#pragma unroll
      for (int j = 0; j < 4; ++j) {
        int e = e0 + w * 16 + (l >> 4) * 4 + j;
        if (e < E) {
          float a = acc[j];
          float z = a / (1.f + expf(-a)) * 0.125f;    // silu, fold 1/sqrt(64)
          h2s[((size_t)(e >> 4) * 4 + s) * 512 + ((e & 15) + 16 * hh) * 8 + i] =
              __float2bfloat16(z);
        }
      }
    }
  } else {
    // head-init (replaces the memset node; must precede k_gemm's list build)
    int d = (b - NW - NM) * 256 + tid;
    if (d < n_dst) head[d] = -1;
  }
}

// ---------- GEMM node: [sh + list-build blocks] + [GEMM + x-contraction blocks] ----------
// 1D grid: bid < NL -> sh+list (consumed only by k_gather, a later node);
// else gemm champion body (decode blk = gvb/3, l3 = gvb%3).
__global__ __launch_bounds__(256, 2) void k_gemm(
    const u16* __restrict__ h2s, const u16* __restrict__ W2s,
    const float* __restrict__ hsrc, const int* __restrict__ srci,
    const float* __restrict__ b2, const float* __restrict__ ev,
    const int* __restrict__ dst, float* __restrict__ shb,
    int* __restrict__ head, int* __restrict__ nxt,
    float* __restrict__ feat_out, int E, int NL) {
  __shared__ float lds[4160];          // xT[64u][64e] (16KB), then fl[4][1040]
  float* xT = lds;
  float* fl = lds;
  const int tid = threadIdx.x, lane = tid & 63, wave = tid >> 6;

  if ((int)blockIdx.x < NL) {
    // spherical harmonics + linked-list build
    int e = blockIdx.x * 256 + tid;
    if (e < E) {
      float vx = ev[e * 3 + 0], vy = ev[e * 3 + 1], vz = ev[e * 3 + 2];
      float nrm = fmaxf(sqrtf(vx * vx + vy * vy + vz * vz), 1e-9f);
      float x = vx / nrm, y = vy / nrm, z = vz / nrm;
      const float SQ3 = 1.7320508075688772f, SQ5 = 2.2360679774997896f,
                  SQ15 = 3.872983346207417f;
      float* sp = shb + (size_t)e * 9;
      sp[0] = 1.f;
      sp[1] = SQ3 * x; sp[2] = SQ3 * y; sp[3] = SQ3 * z;
      sp[4] = SQ15 * x * y; sp[5] = SQ15 * y * z;
      sp[6] = 0.5f * SQ5 * (3.f * z * z - 1.f);
      sp[7] = SQ15 * x * z;
      sp[8] = 0.5f * SQ15 * (x * x - y * y);
      nxt[e] = atomicExch(&head[dst[e]], e);
    }
    return;
  }

  const int gvb = blockIdx.x - NL;
  const int blk = gvb / 3, l3 = gvb - 3 * blk;
  const int c = lane & 15, g = lane >> 4;

  // stage x transposed (wave w stages u-rows [w*16, w*16+16))
  {
    int e = lane, u0 = wave * 16;
    int eg = min(blk * 64 + e, E - 1);
    const float* xr = hsrc + (size_t)srci[eg] * 64 + u0;
#pragma unroll
    for (int k = 0; k < 16; ++k) xT[(u0 + k) * 64 + e] = xr[k];
  }
  // A fragments: 4 M-tiles x 4 k-steps
  short8 af[4][4];
#pragma unroll
  for (int mt = 0; mt < 4; ++mt)
#pragma unroll
    for (int s = 0; s < 4; ++s)
      af[mt][s] = *(const short8*)(h2s + ((size_t)((blk * 4 + mt) * 4 + s) * 64 + lane) * 8);
  __syncthreads();

  float feat[4][4] = {};               // [mt][j], this l-path, this wave's u-range
  const int T0 = l3 * 64 + wave * 16;
  const u16* Bg = W2s + (size_t)T0 * 2048;
  const float* b2g = b2 + T0 * 16 + c;

#pragma unroll
  for (int k = 0; k < 16; ++k) {       // wave's 16 N-tiles, no barriers
    short8 bf[4];
#pragma unroll
    for (int s = 0; s < 4; ++s)
      bf[s] = *(const short8*)(Bg + ((size_t)(k * 4 + s) * 64 + lane) * 8);
    float b2v = 0.125f * b2g[k * 16];
#pragma unroll
    for (int mt = 0; mt < 4; ++mt) {
      f32x4 acc = {b2v, b2v, b2v, b2v};
#pragma unroll
      for (int s = 0; s < 4; ++s)
        acc = __builtin_amdgcn_mfma_f32_16x16x32_bf16(af[mt][s], bf[s], acc, 0, 0, 0);
      const float4 xv = *(const float4*)&xT[(wave * 16 + k) * 64 + mt * 16 + g * 4];
#pragma unroll
      for (int j = 0; j < 4; ++j)
        feat[mt][j] = fmaf((&xv.x)[j], acc[j], feat[mt][j]);
    }
  }

  // cross-wave feat reduction in LDS (reuses xT space — barrier first)
  __syncthreads();
#pragma unroll
  for (int mt = 0; mt < 4; ++mt)
#pragma unroll
    for (int j = 0; j < 4; ++j)
      fl[wave * 1040 + (mt * 16 + g * 4 + j) * 16 + c] = feat[mt][j];
  __syncthreads();

  // epilogue: sum the 4 wave-partials, store compact feat slice for this l3
#pragma unroll
  for (int r = 0; r < 4; ++r) {
    int p = r * 256 + tid;             // 1024 = 64 edges x 16 v
    int eloc = p >> 4, v = p & 15;
    float f = fl[p] + fl[1040 + p] + fl[2080 + p] + fl[3120 + p];
    int e = blk * 64 + eloc;
    if (e < E) feat_out[(size_t)e * 48 + l3 * 16 + v] = f;
  }
}

// ---------- gather: one wave per dst; walk linked list; apply sh; mean ----------
__global__ void k_gather(const float* __restrict__ feat, const float* __restrict__ shb,
                         const int* __restrict__ head, const int* __restrict__ nxt,
                         float* __restrict__ out, int n_dst) {
  int d = blockIdx.x * 4 + (threadIdx.x >> 6);
  int lane = threadIdx.x & 63;
  if (d >= n_dst) return;
  int fi[4], si[4];
#pragma unroll
  for (int r = 0; r < 4; ++r) {
    int o = lane * 4 + r;
    if (o < 16)      { fi[r] = o;                 si[r] = 0; }        // sh[0] == 1
    else if (o < 64) { int id = o - 16; fi[r] = 16 + id / 3; si[r] = 1 + id % 3; }
    else             { int id = o - 64; fi[r] = 32 + id / 5; si[r] = 4 + id % 5; }
  }
  int e = head[d];                     // same addr across lanes -> broadcast load
  float4 acc = {0.f, 0.f, 0.f, 0.f};
  int deg = 0;
  while (e >= 0) {
    int en = nxt[e];                   // issue next-pointer first (chase overlap)
    if (lane < 36) {
      const float* fp = feat + (size_t)e * 48;
      const float* sp = shb + (size_t)e * 9;
#pragma unroll
      for (int r = 0; r < 4; ++r)
        (&acc.x)[r] = fmaf(fp[fi[r]], sp[si[r]], (&acc.x)[r]);
    }
    ++deg;
    e = en;
  }
  if (lane < 36) {
    float inv = 1.f / (float)max(deg, 1);
    acc.x *= inv; acc.y *= inv; acc.z *= inv; acc.w *= inv;
    *(float4*)&out[(size_t)d * OUTD + lane * 4] = acc;
  }
}

extern "C" void kernel_launch(void* const* d_in, const int* in_sizes, int n_in,
                              void* d_out, int out_size, void* d_ws, size_t ws_size,
                              hipStream_t stream) {
  const float* h_src        = (const float*)d_in[0];
  const float* edge_vec     = (const float*)d_in[1];
  const float* edge_scalars = (const float*)d_in[2];
  const float* W1           = (const float*)d_in[3];
  const float* b1           = (const float*)d_in[4];
  const float* W2           = (const float*)d_in[5];
  const float* b2           = (const float*)d_in[6];
  const int*   src_idx      = (const int*)d_in[7];
  const int*   dst_idx      = (const int*)d_in[8];

  const int E = in_sizes[1] / 3;
  const int n_dst = out_size / OUTD;
  const int nblk64 = (E + 63) / 64;
  const size_t E_pad = (size_t)nblk64 * 64;

  char* w = (char*)d_ws;
  auto al = [](size_t x) { return (x + 255) & ~(size_t)255; };
  size_t o = 0;
  float* shb = (float*)(w + o);                   o += al(E_pad * 9 * 4);
  __hip_bfloat16* h2s = (__hip_bfloat16*)(w + o); o += al(E_pad * 128 * 2);
  __hip_bfloat16* W2s = (__hip_bfloat16*)(w + o); o += al((size_t)128 * 3072 * 2);
  float* featb = (float*)(w + o);                 o += al(E_pad * 48 * 4);
  int* head  = (int*)(w + o);                     o += al((size_t)n_dst * 4);
  int* nxt   = (int*)(w + o);                     o += al((size_t)E * 4);

  const int NW = (16 * WNUMEL) / 256;             // 192 vectorized w2s blocks
  const int NM = (E + 63) / 64;                   // mfma-mlp blocks (64 edges each)
  const int NH = (n_dst + 255) / 256;             // head-init blocks
  const int NL = (E + 255) / 256;                 // sh + list blocks (in k_gemm node)

  k_pre<<<NW + NM + NH, 256, 0, stream>>>(W2, W2s, edge_scalars, W1, b1, h2s,
                                          head, E, n_dst, NW, NM);
  k_gemm<<<NL + nblk64 * 3, 256, 0, stream>>>(
      (const u16*)h2s, (const u16*)W2s, h_src, src_idx, b2,
      edge_vec, dst_idx, shb, head, nxt, featb, E, NL);
  k_gather<<<(n_dst + 3) / 4, 256, 0, stream>>>(featb, shb, head, nxt,
                                                (float*)d_out, n_dst);
}